// Round 1
// 760.998 us; speedup vs baseline: 1.2466x; 1.2466x over previous
//
#include <hip/hip_runtime.h>

// SparseAffinity_Propagate: CSPN-style 8-neighbor propagation, 24 iterations.
// B=8, H=W=768. Offsets (dy,dx): (-5,0)(-1,0)(0,5)(0,1)(5,0)(1,0)(0,-5)(0,-1)
//
// Fusion (R0): result = sum_c (A*w_c) * prev[p+off_c] + Bias
// R1: weights fp16 AoS (16 B/px), bias fp32 -> 28 B/px per step.
// R2: 4 px/thread, all vmem as aligned 16B vectors (15 insts/4px vs 44).
// R3: batch->XCD block remap for step kernel. Old grid (1,768,8) gave
//     linear id = y + 768*b -> XCD = y%8, so the 5 row-blocks reading a
//     given prev row (y-5,y-1,y,y+1,y+5) landed on 5 DIFFERENT XCD L2s:
//     prev was filled 5x (208 MB/step fabric traffic = 5.9 TB/s = ceiling).
//     New: 1-D grid, b = L&7, y = L>>3 -> one batch per XCD (round-robin
//     dispatch) or one contiguous row band (chunked dispatch); either way
//     all readers of a prev row are co-XCD -> prev+next L2-resident,
//     ~133 MB/step. Numerically identical.

#define HH 768
#define WW 768
#define BATCH 8
#define PLANE (HH * WW)           // 589824
#define TOTAL (BATCH * PLANE)     // 4718592
#define NITER 24

#define DYS {-5, -1, 0, 0, 5, 1, 0, 0}
#define DXS {0, 0, 5, 1, 0, 0, -5, -1}

typedef _Float16 half8 __attribute__((ext_vector_type(8)));
typedef float f4 __attribute__((ext_vector_type(4)));

__device__ __forceinline__ f4 ldf4(const float* p) { return *(const f4*)p; }

// ---------------------------------------------------------------------------
// Precompute pre-scaled weights (fp16 AoS, 16 B/px) + fp32 bias.
// Block = 192 threads = one row (4 px/thread). Grid (1, 768, 8).
// (No cross-block reuse in this kernel -> no XCD remap needed.)
// ---------------------------------------------------------------------------
__global__ __launch_bounds__(192) void precompute_kernel(
    const float* __restrict__ g,       // (B,8,H,W)
    const float* __restrict__ blur,    // (B,1,H,W)
    const float* __restrict__ sparse,  // (B,1,H,W)
    half8* __restrict__ wout,          // (B*H*W) x 8 fp16  (AoS)
    float* __restrict__ bias)          // (B*H*W)
{
    const int x0 = 4 * threadIdx.x;
    const int y  = blockIdx.y;
    const int b  = blockIdx.z;
    const float* gb = g + (size_t)b * 8 * PLANE;
    const int rowb = y * WW;
    const int pidx = b * PLANE + rowb + x0;

    f4 wv[8];
    if (x0 >= 8 && x0 <= 756) {
        const f4 zero = (f4)0.f;
        // dy planes (aligned, row-guarded; guards are block-uniform)
        wv[0] = (y >= 5)      ? ldf4(gb + 0 * PLANE + (y - 5) * WW + x0) : zero;
        wv[1] = (y >= 1)      ? ldf4(gb + 1 * PLANE + (y - 1) * WW + x0) : zero;
        wv[4] = (y <= HH - 6) ? ldf4(gb + 4 * PLANE + (y + 5) * WW + x0) : zero;
        wv[5] = (y <= HH - 2) ? ldf4(gb + 5 * PLANE + (y + 1) * WW + x0) : zero;
        // dx planes: two aligned f4 loads each, component-select the shift
        {   // c=2, dx=+5 -> x0+5..x0+8
            f4 a = ldf4(gb + 2 * PLANE + rowb + x0 + 4);
            f4 bq = ldf4(gb + 2 * PLANE + rowb + x0 + 8);
            wv[2] = f4{a[1], a[2], a[3], bq[0]};
        }
        {   // c=3, dx=+1 -> x0+1..x0+4
            f4 a = ldf4(gb + 3 * PLANE + rowb + x0);
            f4 bq = ldf4(gb + 3 * PLANE + rowb + x0 + 4);
            wv[3] = f4{a[1], a[2], a[3], bq[0]};
        }
        {   // c=6, dx=-5 -> x0-5..x0-2
            f4 a = ldf4(gb + 6 * PLANE + rowb + x0 - 8);
            f4 bq = ldf4(gb + 6 * PLANE + rowb + x0 - 4);
            wv[6] = f4{a[3], bq[0], bq[1], bq[2]};
        }
        {   // c=7, dx=-1 -> x0-1..x0+2
            f4 a = ldf4(gb + 7 * PLANE + rowb + x0 - 4);
            f4 bq = ldf4(gb + 7 * PLANE + rowb + x0);
            wv[7] = f4{a[3], bq[0], bq[1], bq[2]};
        }
    } else {
        // Edge threads: guarded scalar gathers
        const int dy[8] = DYS;
        const int dx[8] = DXS;
#pragma unroll
        for (int c = 0; c < 8; ++c) {
#pragma unroll
            for (int j = 0; j < 4; ++j) {
                int yy = y + dy[c];
                int xx = x0 + j + dx[c];
                float v = 0.f;
                if (yy >= 0 && yy < HH && xx >= 0 && xx < WW)
                    v = gb[c * PLANE + yy * WW + xx];
                wv[c][j] = v;
            }
        }
    }

    f4 raw = ldf4(blur + pidx);
    f4 sd  = ldf4(sparse + pidx);
    f4 bout;
#pragma unroll
    for (int j = 0; j < 4; ++j) {
        float abssum = 0.f;
#pragma unroll
        for (int c = 0; c < 8; ++c) abssum += fabsf(wv[c][j]);
        float inv = 1.f / fmaxf(abssum, 1e-6f);
        float gs = 0.f;
#pragma unroll
        for (int c = 0; c < 8; ++c) gs += wv[c][j] * inv;
        float s = sd[j];
        float m = (s > 0.f) ? 1.f : ((s < 0.f) ? -1.f : 0.f);
        float A = 1.f - m;
        bout[j] = (A * (1.f - gs) + m) * raw[j];
        float Ai = A * inv;
        half8 hv;
#pragma unroll
        for (int c = 0; c < 8; ++c) hv[c] = (_Float16)(Ai * wv[c][j]);
        wout[pidx + j] = hv;
    }
    *(f4*)(bias + pidx) = bout;
}

// ---------------------------------------------------------------------------
// One propagation step: out = sum_c w_c * prev[p+off_c] + bias
// Block = 192 threads = one row (4 px/thread). Grid (6144, 1, 1):
//   b = blockIdx.x & 7, y = blockIdx.x >> 3  -> batch-per-XCD partition.
// ---------------------------------------------------------------------------
__global__ __launch_bounds__(192) void step_kernel(
    const half8* __restrict__ w,     // (B*H*W) x 8 fp16
    const float* __restrict__ bias,  // (B*H*W)
    const float* __restrict__ prev,  // (B,H,W)
    float* __restrict__ next)        // (B,H,W)
{
    const int L  = blockIdx.x;
    const int b  = L & 7;            // XCD = L % 8 under round-robin dispatch
    const int y  = L >> 3;
    const int x0 = 4 * threadIdx.x;
    const int rowb = y * WW;
    const int pidx = b * PLANE + rowb + x0;
    const float* pb = prev + b * PLANE;

    half8 hv0 = w[pidx + 0];
    half8 hv1 = w[pidx + 1];
    half8 hv2 = w[pidx + 2];
    half8 hv3 = w[pidx + 3];
    f4 acc = ldf4(bias + pidx);

    if (x0 >= 8 && x0 <= 756) {
        const f4 zero = (f4)0.f;
        // dy taps (aligned, block-uniform guards)
        f4 um5 = (y >= 5)      ? ldf4(pb + (y - 5) * WW + x0) : zero;
        f4 um1 = (y >= 1)      ? ldf4(pb + (y - 1) * WW + x0) : zero;
        f4 dp5 = (y <= HH - 6) ? ldf4(pb + (y + 5) * WW + x0) : zero;
        f4 dp1 = (y <= HH - 2) ? ldf4(pb + (y + 1) * WW + x0) : zero;
        // row y: 5 aligned f4 covering [x0-8, x0+11]
        f4 m2 = ldf4(pb + rowb + x0 - 8);
        f4 m1 = ldf4(pb + rowb + x0 - 4);
        f4 c0 = ldf4(pb + rowb + x0);
        f4 p1 = ldf4(pb + rowb + x0 + 4);
        f4 p2 = ldf4(pb + rowb + x0 + 8);
        f4 tm5 = f4{m2[3], m1[0], m1[1], m1[2]};   // dx=-5
        f4 tm1 = f4{m1[3], c0[0], c0[1], c0[2]};   // dx=-1
        f4 tp1 = f4{c0[1], c0[2], c0[3], p1[0]};   // dx=+1
        f4 tp5 = f4{p1[1], p1[2], p1[3], p2[0]};   // dx=+5

        // c order: 0:(-5,0) 1:(-1,0) 2:(0,+5) 3:(0,+1) 4:(+5,0) 5:(+1,0) 6:(0,-5) 7:(0,-1)
        acc[0] = fmaf((float)hv0[0], um5[0], acc[0]);
        acc[1] = fmaf((float)hv1[0], um5[1], acc[1]);
        acc[2] = fmaf((float)hv2[0], um5[2], acc[2]);
        acc[3] = fmaf((float)hv3[0], um5[3], acc[3]);

        acc[0] = fmaf((float)hv0[1], um1[0], acc[0]);
        acc[1] = fmaf((float)hv1[1], um1[1], acc[1]);
        acc[2] = fmaf((float)hv2[1], um1[2], acc[2]);
        acc[3] = fmaf((float)hv3[1], um1[3], acc[3]);

        acc[0] = fmaf((float)hv0[2], tp5[0], acc[0]);
        acc[1] = fmaf((float)hv1[2], tp5[1], acc[1]);
        acc[2] = fmaf((float)hv2[2], tp5[2], acc[2]);
        acc[3] = fmaf((float)hv3[2], tp5[3], acc[3]);

        acc[0] = fmaf((float)hv0[3], tp1[0], acc[0]);
        acc[1] = fmaf((float)hv1[3], tp1[1], acc[1]);
        acc[2] = fmaf((float)hv2[3], tp1[2], acc[2]);
        acc[3] = fmaf((float)hv3[3], tp1[3], acc[3]);

        acc[0] = fmaf((float)hv0[4], dp5[0], acc[0]);
        acc[1] = fmaf((float)hv1[4], dp5[1], acc[1]);
        acc[2] = fmaf((float)hv2[4], dp5[2], acc[2]);
        acc[3] = fmaf((float)hv3[4], dp5[3], acc[3]);

        acc[0] = fmaf((float)hv0[5], dp1[0], acc[0]);
        acc[1] = fmaf((float)hv1[5], dp1[1], acc[1]);
        acc[2] = fmaf((float)hv2[5], dp1[2], acc[2]);
        acc[3] = fmaf((float)hv3[5], dp1[3], acc[3]);

        acc[0] = fmaf((float)hv0[6], tm5[0], acc[0]);
        acc[1] = fmaf((float)hv1[6], tm5[1], acc[1]);
        acc[2] = fmaf((float)hv2[6], tm5[2], acc[2]);
        acc[3] = fmaf((float)hv3[6], tm5[3], acc[3]);

        acc[0] = fmaf((float)hv0[7], tm1[0], acc[0]);
        acc[1] = fmaf((float)hv1[7], tm1[1], acc[1]);
        acc[2] = fmaf((float)hv2[7], tm1[2], acc[2]);
        acc[3] = fmaf((float)hv3[7], tm1[3], acc[3]);
    } else {
        const int dy[8] = DYS;
        const int dx[8] = DXS;
        half8 hvs[4] = {hv0, hv1, hv2, hv3};
#pragma unroll
        for (int j = 0; j < 4; ++j) {
#pragma unroll
            for (int c = 0; c < 8; ++c) {
                int yy = y + dy[c];
                int xx = x0 + j + dx[c];
                float n = 0.f;
                if (yy >= 0 && yy < HH && xx >= 0 && xx < WW)
                    n = pb[yy * WW + xx];
                acc[j] = fmaf((float)hvs[j][c], n, acc[j]);
            }
        }
    }
    *(f4*)(next + pidx) = acc;
}

// ---------------------------------------------------------------------------
// Fallback step (small ws): recompute weights/bias from inputs every step.
// ---------------------------------------------------------------------------
__global__ __launch_bounds__(256) void step_recompute_kernel(
    const float* __restrict__ g,
    const float* __restrict__ blur,
    const float* __restrict__ sparse,
    const float* __restrict__ prev,
    float* __restrict__ next)
{
    const int dy[8] = DYS;
    const int dx[8] = DXS;
    int x = blockIdx.x * blockDim.x + threadIdx.x;
    int y = blockIdx.y;
    int b = blockIdx.z;
    if (x >= WW) return;

    const float* gb = g + (size_t)b * 8 * PLANE;
    float w[8];
    float abssum = 0.f;
#pragma unroll
    for (int c = 0; c < 8; ++c) {
        int yy = y + dy[c];
        int xx = x + dx[c];
        float v = 0.f;
        if (yy >= 0 && yy < HH && xx >= 0 && xx < WW)
            v = gb[c * PLANE + yy * WW + xx];
        w[c] = v;
        abssum += fabsf(v);
    }
    float inv = 1.f / fmaxf(abssum, 1e-6f);
    float gs = 0.f;
#pragma unroll
    for (int c = 0; c < 8; ++c) {
        w[c] *= inv;
        gs += w[c];
    }
    int pidx = b * PLANE + y * WW + x;
    float sd = sparse[pidx];
    float m = (sd > 0.f) ? 1.f : ((sd < 0.f) ? -1.f : 0.f);
    float A = 1.f - m;
    float raw = blur[pidx];

    const float* pb = prev + b * PLANE;
    float acc = 0.f;
#pragma unroll
    for (int c = 0; c < 8; ++c) {
        int yy = y + dy[c];
        int xx = x + dx[c];
        float n = 0.f;
        if (yy >= 0 && yy < HH && xx >= 0 && xx < WW)
            n = pb[yy * WW + xx];
        acc = fmaf(A * w[c], n, acc);
    }
    next[pidx] = acc + (A * (1.f - gs) + m) * raw;
}

// ---------------------------------------------------------------------------
extern "C" void kernel_launch(void* const* d_in, const int* in_sizes, int n_in,
                              void* d_out, int out_size, void* d_ws, size_t ws_size,
                              hipStream_t stream) {
    const float* g      = (const float*)d_in[0];  // guidance (B,8,H,W)
    const float* blur   = (const float*)d_in[1];  // blur_depth (B,1,H,W)
    const float* sparse = (const float*)d_in[2];  // sparse_depth (B,1,H,W)
    float* out = (float*)d_out;

    dim3 blockPre(192, 1, 1);        // one row, 4 px/thread
    dim3 gridPre(1, HH, BATCH);      // precompute: 1 x 768 x 8

    dim3 blockStep(192, 1, 1);
    dim3 gridStep(HH * BATCH, 1, 1); // step: 6144 linear blocks, b=L&7,y=L>>3

    // fast path: fp16 AoS weights (16 B/px) + fp32 bias + ping buffer
    const size_t need_fast = (size_t)TOTAL * 16 + (size_t)TOTAL * 4 * 2;

    if (ws_size >= need_fast) {
        half8* w    = (half8*)d_ws;                       // TOTAL x 16 B
        float* bias = (float*)((char*)d_ws + (size_t)TOTAL * 16);
        float* r0   = bias + TOTAL;

        precompute_kernel<<<gridPre, blockPre, 0, stream>>>(g, blur, sparse, w, bias);

        const float* prev = blur;
        for (int it = 0; it < NITER; ++it) {
            float* nxt = (it % 2 == 0) ? r0 : out;  // it=23 -> out
            step_kernel<<<gridStep, blockStep, 0, stream>>>(w, bias, prev, nxt);
            prev = nxt;
        }
    } else {
        // Fallback: only one ping buffer in ws; recompute weights each step.
        dim3 block2(256, 1, 1);
        dim3 grid2(WW / 256, HH, BATCH);
        float* r0 = (float*)d_ws;
        const float* prev = blur;
        for (int it = 0; it < NITER; ++it) {
            float* nxt = (it % 2 == 0) ? r0 : out;
            step_recompute_kernel<<<grid2, block2, 0, stream>>>(g, blur, sparse,
                                                                prev, nxt);
            prev = nxt;
        }
    }
}

// Round 2
// 748.488 us; speedup vs baseline: 1.2675x; 1.0167x over previous
//
#include <hip/hip_runtime.h>

// SparseAffinity_Propagate: CSPN-style 8-neighbor propagation, 24 iterations.
// B=8, H=W=768. Offsets (dy,dx): (-5,0)(-1,0)(0,5)(0,1)(5,0)(1,0)(0,-5)(0,-1)
//
// Fusion (R0): result = sum_c (A*w_c) * prev[p+off_c] + Bias
// R1: weights fp16 AoS (16 B/px), bias fp32 -> 28 B/px per step.
// R2: 4 px/thread, all vmem as aligned 16B vectors.
// R3: batch->XCD block remap for step kernel (b=L&7 -> one batch per XCD L2);
//     killed the 5x cross-XCD refill of prev. 948 -> 761 us.
// R4: w layout j-planes. Old AoS w[pidx+j] gave lane-stride 64B / 16B payload
//     -> 4 quarter-line L2 requests per line (4.7M requests/step on the
//     75.5 MB w stream, both step-loads and precompute-stores). New layout
//     w[j*NG + pg] (pg = pixel-group = pidx/4, NG = TOTAL/4): every w access
//     is lane-stride 16B -> dense full-line transactions, 1/4 the requests.
//     Same bytes, bit-identical numerics.

#define HH 768
#define WW 768
#define BATCH 8
#define PLANE (HH * WW)           // 589824
#define TOTAL (BATCH * PLANE)     // 4718592
#define NG (TOTAL / 4)            // 1179648 pixel-groups
#define NITER 24

#define DYS {-5, -1, 0, 0, 5, 1, 0, 0}
#define DXS {0, 0, 5, 1, 0, 0, -5, -1}

typedef _Float16 half8 __attribute__((ext_vector_type(8)));
typedef float f4 __attribute__((ext_vector_type(4)));

__device__ __forceinline__ f4 ldf4(const float* p) { return *(const f4*)p; }

// ---------------------------------------------------------------------------
// Precompute pre-scaled weights (fp16, j-plane layout) + fp32 bias.
// Block = 192 threads = one row (4 px/thread). Grid (1, 768, 8).
// ---------------------------------------------------------------------------
__global__ __launch_bounds__(192) void precompute_kernel(
    const float* __restrict__ g,       // (B,8,H,W)
    const float* __restrict__ blur,    // (B,1,H,W)
    const float* __restrict__ sparse,  // (B,1,H,W)
    half8* __restrict__ wout,          // 4 planes x NG half8 (j-plane layout)
    float* __restrict__ bias)          // (B*H*W)
{
    const int x0 = 4 * threadIdx.x;
    const int y  = blockIdx.y;
    const int b  = blockIdx.z;
    const float* gb = g + (size_t)b * 8 * PLANE;
    const int rowb = y * WW;
    const int pidx = b * PLANE + rowb + x0;
    const int pg   = pidx >> 2;        // pixel-group index

    f4 wv[8];
    if (x0 >= 8 && x0 <= 756) {
        const f4 zero = (f4)0.f;
        // dy planes (aligned, row-guarded; guards are block-uniform)
        wv[0] = (y >= 5)      ? ldf4(gb + 0 * PLANE + (y - 5) * WW + x0) : zero;
        wv[1] = (y >= 1)      ? ldf4(gb + 1 * PLANE + (y - 1) * WW + x0) : zero;
        wv[4] = (y <= HH - 6) ? ldf4(gb + 4 * PLANE + (y + 5) * WW + x0) : zero;
        wv[5] = (y <= HH - 2) ? ldf4(gb + 5 * PLANE + (y + 1) * WW + x0) : zero;
        // dx planes: two aligned f4 loads each, component-select the shift
        {   // c=2, dx=+5 -> x0+5..x0+8
            f4 a = ldf4(gb + 2 * PLANE + rowb + x0 + 4);
            f4 bq = ldf4(gb + 2 * PLANE + rowb + x0 + 8);
            wv[2] = f4{a[1], a[2], a[3], bq[0]};
        }
        {   // c=3, dx=+1 -> x0+1..x0+4
            f4 a = ldf4(gb + 3 * PLANE + rowb + x0);
            f4 bq = ldf4(gb + 3 * PLANE + rowb + x0 + 4);
            wv[3] = f4{a[1], a[2], a[3], bq[0]};
        }
        {   // c=6, dx=-5 -> x0-5..x0-2
            f4 a = ldf4(gb + 6 * PLANE + rowb + x0 - 8);
            f4 bq = ldf4(gb + 6 * PLANE + rowb + x0 - 4);
            wv[6] = f4{a[3], bq[0], bq[1], bq[2]};
        }
        {   // c=7, dx=-1 -> x0-1..x0+2
            f4 a = ldf4(gb + 7 * PLANE + rowb + x0 - 4);
            f4 bq = ldf4(gb + 7 * PLANE + rowb + x0);
            wv[7] = f4{a[3], bq[0], bq[1], bq[2]};
        }
    } else {
        // Edge threads: guarded scalar gathers
        const int dy[8] = DYS;
        const int dx[8] = DXS;
#pragma unroll
        for (int c = 0; c < 8; ++c) {
#pragma unroll
            for (int j = 0; j < 4; ++j) {
                int yy = y + dy[c];
                int xx = x0 + j + dx[c];
                float v = 0.f;
                if (yy >= 0 && yy < HH && xx >= 0 && xx < WW)
                    v = gb[c * PLANE + yy * WW + xx];
                wv[c][j] = v;
            }
        }
    }

    f4 raw = ldf4(blur + pidx);
    f4 sd  = ldf4(sparse + pidx);
    f4 bout;
#pragma unroll
    for (int j = 0; j < 4; ++j) {
        float abssum = 0.f;
#pragma unroll
        for (int c = 0; c < 8; ++c) abssum += fabsf(wv[c][j]);
        float inv = 1.f / fmaxf(abssum, 1e-6f);
        float gs = 0.f;
#pragma unroll
        for (int c = 0; c < 8; ++c) gs += wv[c][j] * inv;
        float s = sd[j];
        float m = (s > 0.f) ? 1.f : ((s < 0.f) ? -1.f : 0.f);
        float A = 1.f - m;
        bout[j] = (A * (1.f - gs) + m) * raw[j];
        float Ai = A * inv;
        half8 hv;
#pragma unroll
        for (int c = 0; c < 8; ++c) hv[c] = (_Float16)(Ai * wv[c][j]);
        wout[(size_t)j * NG + pg] = hv;   // j-plane store: lane-stride 16B, dense
    }
    *(f4*)(bias + pidx) = bout;
}

// ---------------------------------------------------------------------------
// One propagation step: out = sum_c w_c * prev[p+off_c] + bias
// Block = 192 threads = one row (4 px/thread). Grid (6144, 1, 1):
//   b = blockIdx.x & 7, y = blockIdx.x >> 3  -> batch-per-XCD partition.
// ---------------------------------------------------------------------------
__global__ __launch_bounds__(192) void step_kernel(
    const half8* __restrict__ w,     // 4 planes x NG half8
    const float* __restrict__ bias,  // (B*H*W)
    const float* __restrict__ prev,  // (B,H,W)
    float* __restrict__ next)        // (B,H,W)
{
    const int L  = blockIdx.x;
    const int b  = L & 7;            // XCD = L % 8 under round-robin dispatch
    const int y  = L >> 3;
    const int x0 = 4 * threadIdx.x;
    const int rowb = y * WW;
    const int pidx = b * PLANE + rowb + x0;
    const int pg   = pidx >> 2;
    const float* pb = prev + b * PLANE;

    half8 hv0 = w[0 * (size_t)NG + pg];   // dense: lane-stride 16B per inst
    half8 hv1 = w[1 * (size_t)NG + pg];
    half8 hv2 = w[2 * (size_t)NG + pg];
    half8 hv3 = w[3 * (size_t)NG + pg];
    f4 acc = ldf4(bias + pidx);

    if (x0 >= 8 && x0 <= 756) {
        const f4 zero = (f4)0.f;
        // dy taps (aligned, block-uniform guards)
        f4 um5 = (y >= 5)      ? ldf4(pb + (y - 5) * WW + x0) : zero;
        f4 um1 = (y >= 1)      ? ldf4(pb + (y - 1) * WW + x0) : zero;
        f4 dp5 = (y <= HH - 6) ? ldf4(pb + (y + 5) * WW + x0) : zero;
        f4 dp1 = (y <= HH - 2) ? ldf4(pb + (y + 1) * WW + x0) : zero;
        // row y: 5 aligned f4 covering [x0-8, x0+11]
        f4 m2 = ldf4(pb + rowb + x0 - 8);
        f4 m1 = ldf4(pb + rowb + x0 - 4);
        f4 c0 = ldf4(pb + rowb + x0);
        f4 p1 = ldf4(pb + rowb + x0 + 4);
        f4 p2 = ldf4(pb + rowb + x0 + 8);
        f4 tm5 = f4{m2[3], m1[0], m1[1], m1[2]};   // dx=-5
        f4 tm1 = f4{m1[3], c0[0], c0[1], c0[2]};   // dx=-1
        f4 tp1 = f4{c0[1], c0[2], c0[3], p1[0]};   // dx=+1
        f4 tp5 = f4{p1[1], p1[2], p1[3], p2[0]};   // dx=+5

        // c order: 0:(-5,0) 1:(-1,0) 2:(0,+5) 3:(0,+1) 4:(+5,0) 5:(+1,0) 6:(0,-5) 7:(0,-1)
        acc[0] = fmaf((float)hv0[0], um5[0], acc[0]);
        acc[1] = fmaf((float)hv1[0], um5[1], acc[1]);
        acc[2] = fmaf((float)hv2[0], um5[2], acc[2]);
        acc[3] = fmaf((float)hv3[0], um5[3], acc[3]);

        acc[0] = fmaf((float)hv0[1], um1[0], acc[0]);
        acc[1] = fmaf((float)hv1[1], um1[1], acc[1]);
        acc[2] = fmaf((float)hv2[1], um1[2], acc[2]);
        acc[3] = fmaf((float)hv3[1], um1[3], acc[3]);

        acc[0] = fmaf((float)hv0[2], tp5[0], acc[0]);
        acc[1] = fmaf((float)hv1[2], tp5[1], acc[1]);
        acc[2] = fmaf((float)hv2[2], tp5[2], acc[2]);
        acc[3] = fmaf((float)hv3[2], tp5[3], acc[3]);

        acc[0] = fmaf((float)hv0[3], tp1[0], acc[0]);
        acc[1] = fmaf((float)hv1[3], tp1[1], acc[1]);
        acc[2] = fmaf((float)hv2[3], tp1[2], acc[2]);
        acc[3] = fmaf((float)hv3[3], tp1[3], acc[3]);

        acc[0] = fmaf((float)hv0[4], dp5[0], acc[0]);
        acc[1] = fmaf((float)hv1[4], dp5[1], acc[1]);
        acc[2] = fmaf((float)hv2[4], dp5[2], acc[2]);
        acc[3] = fmaf((float)hv3[4], dp5[3], acc[3]);

        acc[0] = fmaf((float)hv0[5], dp1[0], acc[0]);
        acc[1] = fmaf((float)hv1[5], dp1[1], acc[1]);
        acc[2] = fmaf((float)hv2[5], dp1[2], acc[2]);
        acc[3] = fmaf((float)hv3[5], dp1[3], acc[3]);

        acc[0] = fmaf((float)hv0[6], tm5[0], acc[0]);
        acc[1] = fmaf((float)hv1[6], tm5[1], acc[1]);
        acc[2] = fmaf((float)hv2[6], tm5[2], acc[2]);
        acc[3] = fmaf((float)hv3[6], tm5[3], acc[3]);

        acc[0] = fmaf((float)hv0[7], tm1[0], acc[0]);
        acc[1] = fmaf((float)hv1[7], tm1[1], acc[1]);
        acc[2] = fmaf((float)hv2[7], tm1[2], acc[2]);
        acc[3] = fmaf((float)hv3[7], tm1[3], acc[3]);
    } else {
        const int dy[8] = DYS;
        const int dx[8] = DXS;
        half8 hvs[4] = {hv0, hv1, hv2, hv3};
#pragma unroll
        for (int j = 0; j < 4; ++j) {
#pragma unroll
            for (int c = 0; c < 8; ++c) {
                int yy = y + dy[c];
                int xx = x0 + j + dx[c];
                float n = 0.f;
                if (yy >= 0 && yy < HH && xx >= 0 && xx < WW)
                    n = pb[yy * WW + xx];
                acc[j] = fmaf((float)hvs[j][c], n, acc[j]);
            }
        }
    }
    *(f4*)(next + pidx) = acc;
}

// ---------------------------------------------------------------------------
// Fallback step (small ws): recompute weights/bias from inputs every step.
// ---------------------------------------------------------------------------
__global__ __launch_bounds__(256) void step_recompute_kernel(
    const float* __restrict__ g,
    const float* __restrict__ blur,
    const float* __restrict__ sparse,
    const float* __restrict__ prev,
    float* __restrict__ next)
{
    const int dy[8] = DYS;
    const int dx[8] = DXS;
    int x = blockIdx.x * blockDim.x + threadIdx.x;
    int y = blockIdx.y;
    int b = blockIdx.z;
    if (x >= WW) return;

    const float* gb = g + (size_t)b * 8 * PLANE;
    float w[8];
    float abssum = 0.f;
#pragma unroll
    for (int c = 0; c < 8; ++c) {
        int yy = y + dy[c];
        int xx = x + dx[c];
        float v = 0.f;
        if (yy >= 0 && yy < HH && xx >= 0 && xx < WW)
            v = gb[c * PLANE + yy * WW + xx];
        w[c] = v;
        abssum += fabsf(v);
    }
    float inv = 1.f / fmaxf(abssum, 1e-6f);
    float gs = 0.f;
#pragma unroll
    for (int c = 0; c < 8; ++c) {
        w[c] *= inv;
        gs += w[c];
    }
    int pidx = b * PLANE + y * WW + x;
    float sd = sparse[pidx];
    float m = (sd > 0.f) ? 1.f : ((sd < 0.f) ? -1.f : 0.f);
    float A = 1.f - m;
    float raw = blur[pidx];

    const float* pb = prev + b * PLANE;
    float acc = 0.f;
#pragma unroll
    for (int c = 0; c < 8; ++c) {
        int yy = y + dy[c];
        int xx = x + dx[c];
        float n = 0.f;
        if (yy >= 0 && yy < HH && xx >= 0 && xx < WW)
            n = pb[yy * WW + xx];
        acc = fmaf(A * w[c], n, acc);
    }
    next[pidx] = acc + (A * (1.f - gs) + m) * raw;
}

// ---------------------------------------------------------------------------
extern "C" void kernel_launch(void* const* d_in, const int* in_sizes, int n_in,
                              void* d_out, int out_size, void* d_ws, size_t ws_size,
                              hipStream_t stream) {
    const float* g      = (const float*)d_in[0];  // guidance (B,8,H,W)
    const float* blur   = (const float*)d_in[1];  // blur_depth (B,1,H,W)
    const float* sparse = (const float*)d_in[2];  // sparse_depth (B,1,H,W)
    float* out = (float*)d_out;

    dim3 blockPre(192, 1, 1);        // one row, 4 px/thread
    dim3 gridPre(1, HH, BATCH);      // precompute: 1 x 768 x 8

    dim3 blockStep(192, 1, 1);
    dim3 gridStep(HH * BATCH, 1, 1); // step: 6144 linear blocks, b=L&7,y=L>>3

    // fast path: fp16 j-plane weights (16 B/px) + fp32 bias + ping buffer
    const size_t need_fast = (size_t)TOTAL * 16 + (size_t)TOTAL * 4 * 2;

    if (ws_size >= need_fast) {
        half8* w    = (half8*)d_ws;                       // 4*NG x 16 B
        float* bias = (float*)((char*)d_ws + (size_t)TOTAL * 16);
        float* r0   = bias + TOTAL;

        precompute_kernel<<<gridPre, blockPre, 0, stream>>>(g, blur, sparse, w, bias);

        const float* prev = blur;
        for (int it = 0; it < NITER; ++it) {
            float* nxt = (it % 2 == 0) ? r0 : out;  // it=23 -> out
            step_kernel<<<gridStep, blockStep, 0, stream>>>(w, bias, prev, nxt);
            prev = nxt;
        }
    } else {
        // Fallback: only one ping buffer in ws; recompute weights each step.
        dim3 block2(256, 1, 1);
        dim3 grid2(WW / 256, HH, BATCH);
        float* r0 = (float*)d_ws;
        const float* prev = blur;
        for (int it = 0; it < NITER; ++it) {
            float* nxt = (it % 2 == 0) ? r0 : out;
            step_recompute_kernel<<<grid2, block2, 0, stream>>>(g, blur, sparse,
                                                                prev, nxt);
            prev = nxt;
        }
    }
}